// Round 1
// baseline (4957.478 us; speedup 1.0000x reference)
//
#include <hip/hip_runtime.h>
#include <hip/hip_bf16.h>
#include <cstddef>

// ---------------- dims ----------------
// B=1, S=1024, D=1024, H=16, G=4, HD=64, DFF=4096, V=32000, L=4
#define S_ 1024
#define D_ 1024
#define H_ 16
#define G_ 4
#define HD_ 64
#define DFF_ 4096
#define V_ 32000
#define L_ 4

// ---------------- embedding gather ----------------
__global__ __launch_bounds__(256) void embed_k(const int* __restrict__ x,
                                               const float* __restrict__ emb,
                                               float* __restrict__ H) {
  int s = blockIdx.x;
  int r = x[s];
  const float4* src = (const float4*)(emb + (size_t)r * D_);
  float4* dst = (float4*)(H + (size_t)s * D_);
  dst[threadIdx.x] = src[threadIdx.x];
}

// ---------------- fp32 NT GEMM: C[m,n] = sum_k A[m,k]*B[n,k] + bias[n], scaled ----------------
// A: (M,K) row-major, B: (N,K) row-major. M,N multiples of 64; K multiple of 16.
#define BM 64
#define BN 64
#define BK 16
__global__ __launch_bounds__(256) void gemm_nt(const float* __restrict__ A,
                                               const float* __restrict__ B,
                                               const float* __restrict__ bias,
                                               const float* __restrict__ colscale,
                                               float smul,
                                               float* __restrict__ C,
                                               int M, int N, int K) {
  __shared__ float As[BK][BM];
  __shared__ float Bs[BK][BN];
  const int tid = threadIdx.x;
  const int tx = tid & 15, ty = tid >> 4;
  const int row0 = blockIdx.y * BM, col0 = blockIdx.x * BN;
  // staging: each thread loads one float4 along K for A and B
  const int lr = tid >> 2;           // 0..63 tile row
  const int lk = (tid & 3) * 4;      // 0,4,8,12 k offset
  float acc[4][4] = {};
  for (int k0 = 0; k0 < K; k0 += BK) {
    float4 av = *(const float4*)(A + (size_t)(row0 + lr) * K + k0 + lk);
    float4 bv = *(const float4*)(B + (size_t)(col0 + lr) * K + k0 + lk);
    As[lk + 0][lr] = av.x; As[lk + 1][lr] = av.y; As[lk + 2][lr] = av.z; As[lk + 3][lr] = av.w;
    Bs[lk + 0][lr] = bv.x; Bs[lk + 1][lr] = bv.y; Bs[lk + 2][lr] = bv.z; Bs[lk + 3][lr] = bv.w;
    __syncthreads();
    #pragma unroll
    for (int kk = 0; kk < BK; ++kk) {
      float a[4], b[4];
      *(float4*)a = *(const float4*)(&As[kk][ty * 4]);
      *(float4*)b = *(const float4*)(&Bs[kk][tx * 4]);
      #pragma unroll
      for (int i = 0; i < 4; ++i)
        #pragma unroll
        for (int j = 0; j < 4; ++j)
          acc[i][j] = fmaf(a[i], b[j], acc[i][j]);
    }
    __syncthreads();
  }
  #pragma unroll
  for (int i = 0; i < 4; ++i) {
    int row = row0 + ty * 4 + i;
    #pragma unroll
    for (int j = 0; j < 4; ++j) {
      int col = col0 + tx * 4 + j;
      float v = acc[i][j] + bias[col];
      if (colscale) v *= colscale[col];
      v *= smul;
      C[(size_t)row * N + col] = v;
    }
  }
}

// ---------------- fused RoPE + cosine_norm (+ folded eff^2 * rtd for Q) ----------------
// X: (S, NH*64). One wave per (s, head). sqk == nullptr -> K path (no scale).
__global__ __launch_bounds__(256) void rope_norm(float* __restrict__ X,
                                                 const float* __restrict__ sqk,
                                                 int NH, float rtd) {
  const int idx = blockIdx.x * 4 + (threadIdx.x >> 6);
  const int lane = threadIdx.x & 63;
  const int s = idx / NH, hh = idx - s * NH;
  float* px = X + (size_t)s * NH * 64 + hh * 64;
  float x = px[lane];
  float other = px[lane ^ 32];
  int j = lane & 31;
  float inv = expf(-(float)j * 0.28782313662425572f);  // ln(10000)/32
  float ang = (float)s * inv;
  float c = cosf(ang), sn = sinf(ang);
  float rot = (lane < 32) ? -other : other;
  float val = fmaf(x, c, rot * sn);
  float ssq = val * val;
  #pragma unroll
  for (int off = 32; off; off >>= 1) ssq += __shfl_xor(ssq, off);
  float scale = 1.0f / fmaxf(sqrtf(ssq), 1e-6f);
  if (sqk) {
    float eff = sqk[hh * 64 + lane] * rtd;
    scale *= eff * eff * rtd;  // fold eff^2 (q and k scales) and the sqrt(HD) score scale
  }
  px[lane] = val * scale;
}

// ---------------- flash attention (fp32), 1 wave per query row ----------------
// Q: (S, H*64) already rope+normed+scaled, K: (S, G*64) rope+normed, V: (S, G*64) raw.
__global__ __launch_bounds__(256) void attn_fa(const float* __restrict__ Q,
                                               const float* __restrict__ Kn,
                                               const float* __restrict__ Vr,
                                               float* __restrict__ O) {
  const int head = blockIdx.x;
  const int g = head >> 2;               // HPG = 4 (repeat semantics)
  const int qbase = blockIdx.y * 4;
  const int w = threadIdx.x >> 6, lane = threadIdx.x & 63;
  const int qrow = qbase + w;
  __shared__ float Ks[64][65], Vs[64][65];
  __shared__ float Qs[4][64], Ps[4][64];
  Qs[w][lane] = Q[(size_t)qrow * (H_ * 64) + head * 64 + lane];
  float m = -1e30f, l = 0.f, acc = 0.f;
  const int kbmax = qbase >> 6;
  const int sr = threadIdx.x >> 2;          // stage row 0..63
  const int sc = (threadIdx.x & 3) * 16;    // stage col base
  for (int kb = 0; kb <= kbmax; ++kb) {
    __syncthreads();
    const float* krow = Kn + (size_t)(kb * 64 + sr) * (G_ * 64) + g * 64 + sc;
    const float* vrow = Vr + (size_t)(kb * 64 + sr) * (G_ * 64) + g * 64 + sc;
    #pragma unroll
    for (int jj = 0; jj < 4; ++jj) {
      float4 kv = *(const float4*)(krow + jj * 4);
      Ks[sr][sc + jj * 4 + 0] = kv.x; Ks[sr][sc + jj * 4 + 1] = kv.y;
      Ks[sr][sc + jj * 4 + 2] = kv.z; Ks[sr][sc + jj * 4 + 3] = kv.w;
      float4 vv = *(const float4*)(vrow + jj * 4);
      Vs[sr][sc + jj * 4 + 0] = vv.x; Vs[sr][sc + jj * 4 + 1] = vv.y;
      Vs[sr][sc + jj * 4 + 2] = vv.z; Vs[sr][sc + jj * 4 + 3] = vv.w;
    }
    __syncthreads();
    float s = 0.f;
    #pragma unroll 8
    for (int d = 0; d < 64; ++d) s = fmaf(Qs[w][d], Ks[lane][d], s);
    if (kb * 64 + lane > qrow) s = -1e30f;  // causal mask (prob -> exactly 0)
    float bm = s;
    #pragma unroll
    for (int off = 32; off; off >>= 1) bm = fmaxf(bm, __shfl_xor(bm, off));
    float mnew = fmaxf(m, bm);
    float alpha = __expf(m - mnew);
    float p = __expf(s - mnew);
    float ps = p;
    #pragma unroll
    for (int off = 32; off; off >>= 1) ps += __shfl_xor(ps, off);
    l = l * alpha + ps;
    m = mnew;
    Ps[w][lane] = p;          // wave-private row; within-wave LDS RAW handled by waitcnt
    acc *= alpha;
    #pragma unroll 8
    for (int kk = 0; kk < 64; ++kk) acc = fmaf(Ps[w][kk], Vs[kk][lane], acc);
  }
  O[(size_t)qrow * (H_ * 64) + head * 64 + lane] = acc / l;
}

// ---------------- residual + double cosine_norm: h = cn(h + w*(cn(xin) - h)) ----------------
__global__ __launch_bounds__(256) void resid_norm(float* __restrict__ H,
                                                  const float* __restrict__ Xin,
                                                  const float* __restrict__ eig,
                                                  float rtD) {
  const int row = blockIdx.x, t = threadIdx.x;
  __shared__ float sm1[4], sm2[4];
  float4 xv = *(const float4*)(Xin + (size_t)row * D_ + t * 4);
  float4 hv = *(const float4*)(H + (size_t)row * D_ + t * 4);
  float ss = xv.x * xv.x + xv.y * xv.y + xv.z * xv.z + xv.w * xv.w;
  #pragma unroll
  for (int off = 32; off; off >>= 1) ss += __shfl_xor(ss, off);
  if ((t & 63) == 0) sm1[t >> 6] = ss;
  __syncthreads();
  ss = sm1[0] + sm1[1] + sm1[2] + sm1[3];
  float inv1 = 1.0f / fmaxf(sqrtf(ss), 1e-6f);
  float4 ev = *(const float4*)(eig + t * 4);
  float y[4];
  y[0] = hv.x + ev.x * rtD * (xv.x * inv1 - hv.x);
  y[1] = hv.y + ev.y * rtD * (xv.y * inv1 - hv.y);
  y[2] = hv.z + ev.z * rtD * (xv.z * inv1 - hv.z);
  y[3] = hv.w + ev.w * rtD * (xv.w * inv1 - hv.w);
  float s2 = y[0] * y[0] + y[1] * y[1] + y[2] * y[2] + y[3] * y[3];
  #pragma unroll
  for (int off = 32; off; off >>= 1) s2 += __shfl_xor(s2, off);
  if ((t & 63) == 0) sm2[t >> 6] = s2;
  __syncthreads();
  s2 = sm2[0] + sm2[1] + sm2[2] + sm2[3];
  float inv2 = 1.0f / fmaxf(sqrtf(s2), 1e-6f);
  float4 o = make_float4(y[0] * inv2, y[1] * inv2, y[2] * inv2, y[3] * inv2);
  *(float4*)(H + (size_t)row * D_ + t * 4) = o;
}

// ---------------- swiglu: U = U * silu(G) (scales already applied in GEMM epilogue) ----------------
__global__ __launch_bounds__(256) void swiglu(float* __restrict__ U,
                                              const float* __restrict__ Gt) {
  int i = blockIdx.x * 256 + threadIdx.x;
  float4 u = ((float4*)U)[i];
  float4 g = ((const float4*)Gt)[i];
  u.x *= g.x / (1.f + __expf(-g.x));
  u.y *= g.y / (1.f + __expf(-g.y));
  u.z *= g.z / (1.f + __expf(-g.z));
  u.w *= g.w / (1.f + __expf(-g.w));
  ((float4*)U)[i] = u;
}

// ---------------- row softmax over V=32000 ----------------
__global__ __launch_bounds__(256) void softmax_rows(float* __restrict__ X, int N) {
  const int row = blockIdx.x, t = threadIdx.x;
  float* xr = X + (size_t)row * N;
  __shared__ float sm1[4], sm2[4];
  float m = -1e30f;
  for (int c = t; c < N; c += 256) m = fmaxf(m, xr[c]);
  #pragma unroll
  for (int off = 32; off; off >>= 1) m = fmaxf(m, __shfl_xor(m, off));
  if ((t & 63) == 0) sm1[t >> 6] = m;
  __syncthreads();
  m = fmaxf(fmaxf(sm1[0], sm1[1]), fmaxf(sm1[2], sm1[3]));
  float l = 0.f;
  for (int c = t; c < N; c += 256) l += __expf(xr[c] - m);
  #pragma unroll
  for (int off = 32; off; off >>= 1) l += __shfl_xor(l, off);
  if ((t & 63) == 0) sm2[t >> 6] = l;
  __syncthreads();
  l = sm2[0] + sm2[1] + sm2[2] + sm2[3];
  float inv = 1.0f / l;
  for (int c = t; c < N; c += 256) xr[c] = __expf(xr[c] - m) * inv;
}

// ---------------- launch ----------------
extern "C" void kernel_launch(void* const* d_in, const int* in_sizes, int n_in,
                              void* d_out, int out_size, void* d_ws, size_t ws_size,
                              hipStream_t stream) {
  (void)in_sizes; (void)n_in; (void)out_size; (void)ws_size;
  const int*   x      = (const int*)d_in[0];
  const float* emb    = (const float*)d_in[1];
  const float* qw     = (const float*)d_in[2];
  const float* qbias  = (const float*)d_in[3];
  const float* kw     = (const float*)d_in[4];
  const float* kbias  = (const float*)d_in[5];
  const float* vw     = (const float*)d_in[6];
  const float* vbias  = (const float*)d_in[7];
  const float* sqk    = (const float*)d_in[8];
  const float* ow     = (const float*)d_in[9];
  const float* obias  = (const float*)d_in[10];
  const float* w_in   = (const float*)d_in[11];
  const float* b_in   = (const float*)d_in[12];
  const float* w_gate = (const float*)d_in[13];
  const float* b_gate = (const float*)d_in[14];
  const float* w_out  = (const float*)d_in[15];
  const float* b_out  = (const float*)d_in[16];
  const float* s_u    = (const float*)d_in[17];
  const float* s_v    = (const float*)d_in[18];
  const float* eig_a  = (const float*)d_in[19];
  const float* eig_m  = (const float*)d_in[20];
  const float* out_w  = (const float*)d_in[21];
  const float* out_b  = (const float*)d_in[22];
  const float* s_z    = (const float*)d_in[23];
  float* out = (float*)d_out;

  const float rtd = 8.0f;   // sqrt(HD)
  const float rtD = 32.0f;  // sqrt(D)

  // workspace layout (floats): ~52 MB total
  float* hbuf = (float*)d_ws;                 // S*D
  float* qbuf = hbuf + (size_t)S_ * D_;       // S*D
  float* kbuf = qbuf + (size_t)S_ * D_;       // S*G*HD
  float* vbuf = kbuf + (size_t)S_ * G_ * HD_; // S*G*HD
  float* abuf = vbuf + (size_t)S_ * G_ * HD_; // S*D
  float* tbuf = abuf + (size_t)S_ * D_;       // S*D
  float* ubuf = tbuf + (size_t)S_ * D_;       // S*DFF
  float* gbuf = ubuf + (size_t)S_ * DFF_;     // S*DFF

  embed_k<<<S_, 256, 0, stream>>>(x, emb, hbuf);

  for (int i = 0; i < L_; ++i) {
    gemm_nt<<<dim3(D_ / 64, S_ / 64), 256, 0, stream>>>(
        hbuf, qw + (size_t)i * D_ * D_, qbias + (size_t)i * D_, nullptr, 1.0f,
        qbuf, S_, D_, D_);
    gemm_nt<<<dim3(G_ * HD_ / 64, S_ / 64), 256, 0, stream>>>(
        hbuf, kw + (size_t)i * G_ * HD_ * D_, kbias + (size_t)i * G_ * HD_, nullptr, 1.0f,
        kbuf, S_, G_ * HD_, D_);
    gemm_nt<<<dim3(G_ * HD_ / 64, S_ / 64), 256, 0, stream>>>(
        hbuf, vw + (size_t)i * G_ * HD_ * D_, vbias + (size_t)i * G_ * HD_, nullptr, 1.0f,
        vbuf, S_, G_ * HD_, D_);
    rope_norm<<<S_ * H_ / 4, 256, 0, stream>>>(qbuf, sqk + (size_t)i * H_ * HD_, H_, rtd);
    rope_norm<<<S_ * G_ / 4, 256, 0, stream>>>(kbuf, nullptr, G_, rtd);
    attn_fa<<<dim3(H_, S_ / 4), 256, 0, stream>>>(qbuf, kbuf, vbuf, abuf);
    gemm_nt<<<dim3(D_ / 64, S_ / 64), 256, 0, stream>>>(
        abuf, ow + (size_t)i * D_ * D_, obias + (size_t)i * D_, nullptr, 1.0f,
        tbuf, S_, D_, D_);
    resid_norm<<<S_, 256, 0, stream>>>(hbuf, tbuf, eig_a + (size_t)i * D_, rtD);
    gemm_nt<<<dim3(DFF_ / 64, S_ / 64), 256, 0, stream>>>(
        hbuf, w_in + (size_t)i * DFF_ * D_, b_in + (size_t)i * DFF_,
        s_u + (size_t)i * DFF_, 1.0f, ubuf, S_, DFF_, D_);
    gemm_nt<<<dim3(DFF_ / 64, S_ / 64), 256, 0, stream>>>(
        hbuf, w_gate + (size_t)i * DFF_ * D_, b_gate + (size_t)i * DFF_,
        s_v + (size_t)i * DFF_, rtD, gbuf, S_, DFF_, D_);
    swiglu<<<(S_ * DFF_) / 1024, 256, 0, stream>>>(ubuf, gbuf);
    gemm_nt<<<dim3(D_ / 64, S_ / 64), 256, 0, stream>>>(
        ubuf, w_out + (size_t)i * D_ * DFF_, b_out + (size_t)i * D_, nullptr, 1.0f,
        tbuf, S_, D_, DFF_);
    resid_norm<<<S_, 256, 0, stream>>>(hbuf, tbuf, eig_m + (size_t)i * D_, rtD);
  }

  gemm_nt<<<dim3(V_ / 64, S_ / 64), 256, 0, stream>>>(
      hbuf, out_w, out_b, s_z, rtD, out, S_, V_, D_);
  softmax_rows<<<S_, 256, 0, stream>>>(out, V_);
}